// Round 5
// baseline (336.520 us; speedup 1.0000x reference)
//
#include <hip/hip_runtime.h>

// B=64, S=512, D=256, VOCAB=50000, NC=10, N_STEPS=10 (h=0.1), BN eval.
// RK4 on linear RHS == affine map; 10 steps collapse to z@P10 + c10.
// Round 5: prep = 64 blocks x 4 rows, 6 phases / 5 barriers, N-space
// (polynomials of 0.1*W, no transposed copy), transposed duals for the
// c-chain, node repack fused into final matmul. k_main: per-slice B-fragment
// register prefetch (16 loads in flight before MFMA loop).

typedef short bf16x8 __attribute__((ext_vector_type(8)));
typedef float f32x4 __attribute__((ext_vector_type(4)));

#define NBLK 64

__device__ __forceinline__ unsigned short f2bf(float f) {
  unsigned u = __float_as_uint(f);
  u += 0x7FFFu + ((u >> 16) & 1u);   // RNE; inputs are normal floats
  return (unsigned short)(u >> 16);
}

// grid barrier: release RMW on cnt, last arriver release-stores flag,
// RELAXED polling (no per-poll invalidate), one acquire load on exit.
__device__ __forceinline__ void gsync(unsigned* cnt, unsigned* flag, unsigned phase) {
  __syncthreads();
  if (threadIdx.x == 0) {
    unsigned old = __hip_atomic_fetch_add(cnt, 1u, __ATOMIC_RELEASE, __HIP_MEMORY_SCOPE_AGENT);
    if (old == phase * NBLK - 1)
      __hip_atomic_store(flag, phase, __ATOMIC_RELEASE, __HIP_MEMORY_SCOPE_AGENT);
    while (__hip_atomic_load(flag, __ATOMIC_RELAXED, __HIP_MEMORY_SCOPE_AGENT) < phase)
      __builtin_amdgcn_s_sleep(2);
    (void)__hip_atomic_load(flag, __ATOMIC_ACQUIRE, __HIP_MEMORY_SCOPE_AGENT);
  }
  __syncthreads();
}

// C = A@B rows i0..i0+3, thread j owns column j. Optional transposed dual CT.
__device__ __forceinline__ void mm4rows(const float* __restrict__ A,
                                        const float* __restrict__ B,
                                        float* __restrict__ C,
                                        float* __restrict__ CT,
                                        int i0, int j) {
  float a0 = 0.f, a1 = 0.f, a2 = 0.f, a3 = 0.f;
  const float* Ar = A + (size_t)i0 * 256;
#pragma unroll 8
  for (int k4 = 0; k4 < 64; ++k4) {
    const int k = k4 * 4;
    const float4 r0 = *(const float4*)(Ar + k);
    const float4 r1 = *(const float4*)(Ar + 256 + k);
    const float4 r2 = *(const float4*)(Ar + 512 + k);
    const float4 r3 = *(const float4*)(Ar + 768 + k);
    const float b0 = B[(k + 0) * 256 + j];
    const float b1 = B[(k + 1) * 256 + j];
    const float b2 = B[(k + 2) * 256 + j];
    const float b3 = B[(k + 3) * 256 + j];
    a0 = fmaf(r0.x, b0, fmaf(r0.y, b1, fmaf(r0.z, b2, fmaf(r0.w, b3, a0))));
    a1 = fmaf(r1.x, b0, fmaf(r1.y, b1, fmaf(r1.z, b2, fmaf(r1.w, b3, a1))));
    a2 = fmaf(r2.x, b0, fmaf(r2.y, b1, fmaf(r2.z, b2, fmaf(r2.w, b3, a2))));
    a3 = fmaf(r3.x, b0, fmaf(r3.y, b1, fmaf(r3.z, b2, fmaf(r3.w, b3, a3))));
  }
  C[(i0 + 0) * 256 + j] = a0;
  C[(i0 + 1) * 256 + j] = a1;
  C[(i0 + 2) * 256 + j] = a2;
  C[(i0 + 3) * 256 + j] = a3;
  if (CT) *(float4*)(CT + (size_t)j * 256 + i0) = make_float4(a0, a1, a2, a3);
}

// ---------------- fused prep: 64 blocks x 4 rows, 5 grid barriers ----------------
__global__ __launch_bounds__(256, 1) void k_prep(
    const float* __restrict__ W, const float* __restrict__ bode,
    const float* __restrict__ w3, const float* __restrict__ w4, const float* __restrict__ w5,
    float* mat, unsigned short* slab, unsigned* cnt, unsigned* flag) {
  float* Wp2   = mat;
  float* Wp3   = mat + 65536;
  float* Wp4   = mat + 131072;
  float* Mn    = mat + 196608;
  float* Q2    = mat + 262144;
  float* Q4    = mat + 327680;
  float* Q8    = mat + 393216;
  float* T_W   = mat + 458752;
  float* T_Wp2 = mat + 524288;
  float* T_Wp3 = mat + 589824;
  float* T_Mn  = mat + 655360;
  float* T_Q2  = mat + 720896;
  float* T_Q4  = mat + 786432;
  float* c10g  = mat + 851968;

  const int blk = blockIdx.x;
  const int j = threadIdx.x;
  const int i0 = blk * 4;
  __shared__ float sv[256];

  // ---- S1: Wp2 = W@W (+T_Wp2); T_W dual; conv-weight repack ----
  mm4rows(W, W, Wp2, T_Wp2, i0, j);
  {
    float w0 = W[(i0 + 0) * 256 + j], w1 = W[(i0 + 1) * 256 + j];
    float w2 = W[(i0 + 2) * 256 + j], w3v = W[(i0 + 3) * 256 + j];
    *(float4*)(T_W + (size_t)j * 256 + i0) = make_float4(w0, w1, w2, w3v);
  }
  for (int e = blk * 256 + j; e < 12 * 32768; e += NBLK * 256) {
    int s = e >> 15, r = e & 32767, kd = r >> 7, o = r & 127;
    const float* w; int kk, jj;
    if (s < 3)      { w = w3; kk = 3; jj = s; }
    else if (s < 7) { w = w4; kk = 4; jj = s - 3; }
    else            { w = w5; kk = 5; jj = s - 7; }
    float val = w[(o * 256 + kd) * kk + jj];
    int kc = kd >> 5, quad = (kd >> 3) & 3, q8 = kd & 7;
    slab[s * 32768 + ((kc * 4 + quad) * 128 + o) * 8 + q8] = f2bf(val);
  }
  gsync(cnt, flag, 1);

  // ---- S2: Wp3 = Wp2@W, Wp4 = Wp2@Wp2 (shared A); Mn = Taylor ----
  {
    float p30 = 0.f, p31 = 0.f, p32 = 0.f, p33 = 0.f;
    float p40 = 0.f, p41 = 0.f, p42 = 0.f, p43 = 0.f;
    const float* Ar = Wp2 + (size_t)i0 * 256;
#pragma unroll 4
    for (int k4 = 0; k4 < 64; ++k4) {
      const int k = k4 * 4;
      const float4 r0 = *(const float4*)(Ar + k);
      const float4 r1 = *(const float4*)(Ar + 256 + k);
      const float4 r2 = *(const float4*)(Ar + 512 + k);
      const float4 r3 = *(const float4*)(Ar + 768 + k);
      const float wb0 = W[(k + 0) * 256 + j], wb1 = W[(k + 1) * 256 + j];
      const float wb2 = W[(k + 2) * 256 + j], wb3 = W[(k + 3) * 256 + j];
      const float qb0 = Wp2[(k + 0) * 256 + j], qb1 = Wp2[(k + 1) * 256 + j];
      const float qb2 = Wp2[(k + 2) * 256 + j], qb3 = Wp2[(k + 3) * 256 + j];
      p30 = fmaf(r0.x, wb0, fmaf(r0.y, wb1, fmaf(r0.z, wb2, fmaf(r0.w, wb3, p30))));
      p31 = fmaf(r1.x, wb0, fmaf(r1.y, wb1, fmaf(r1.z, wb2, fmaf(r1.w, wb3, p31))));
      p32 = fmaf(r2.x, wb0, fmaf(r2.y, wb1, fmaf(r2.z, wb2, fmaf(r2.w, wb3, p32))));
      p33 = fmaf(r3.x, wb0, fmaf(r3.y, wb1, fmaf(r3.z, wb2, fmaf(r3.w, wb3, p33))));
      p40 = fmaf(r0.x, qb0, fmaf(r0.y, qb1, fmaf(r0.z, qb2, fmaf(r0.w, qb3, p40))));
      p41 = fmaf(r1.x, qb0, fmaf(r1.y, qb1, fmaf(r1.z, qb2, fmaf(r1.w, qb3, p41))));
      p42 = fmaf(r2.x, qb0, fmaf(r2.y, qb1, fmaf(r2.z, qb2, fmaf(r2.w, qb3, p42))));
      p43 = fmaf(r3.x, qb0, fmaf(r3.y, qb1, fmaf(r3.z, qb2, fmaf(r3.w, qb3, p43))));
    }
    Wp3[(i0 + 0) * 256 + j] = p30; Wp3[(i0 + 1) * 256 + j] = p31;
    Wp3[(i0 + 2) * 256 + j] = p32; Wp3[(i0 + 3) * 256 + j] = p33;
    *(float4*)(T_Wp3 + (size_t)j * 256 + i0) = make_float4(p30, p31, p32, p33);
    Wp4[(i0 + 0) * 256 + j] = p40; Wp4[(i0 + 1) * 256 + j] = p41;
    Wp4[(i0 + 2) * 256 + j] = p42; Wp4[(i0 + 3) * 256 + j] = p43;
    // Mn = I + 0.1W + 0.005 Wp2 + Wp3/6000 + Wp4/240000
    float m[4];
    const float p3s[4] = {p30, p31, p32, p33}, p4s[4] = {p40, p41, p42, p43};
#pragma unroll
    for (int r = 0; r < 4; ++r) {
      const float wv = W[(i0 + r) * 256 + j];
      const float q2 = Wp2[(i0 + r) * 256 + j];
      m[r] = ((i0 + r) == j ? 1.f : 0.f) + 0.1f * wv + 0.005f * q2
             + p3s[r] * (1.f / 6000.f) + p4s[r] * (1.f / 240000.f);
      Mn[(i0 + r) * 256 + j] = m[r];
    }
    *(float4*)(T_Mn + (size_t)j * 256 + i0) = make_float4(m[0], m[1], m[2], m[3]);
  }
  gsync(cnt, flag, 2);

  // ---- S3: Q2 = Mn@Mn ----
  mm4rows(Mn, Mn, Q2, T_Q2, i0, j);
  gsync(cnt, flag, 3);

  // ---- S4: Q4 = Q2@Q2 ----
  mm4rows(Q2, Q2, Q4, T_Q4, i0, j);
  gsync(cnt, flag, 4);

  // ---- S5: Q8 = Q4@Q4 ----
  mm4rows(Q4, Q4, Q8, nullptr, i0, j);
  gsync(cnt, flag, 5);

  // ---- S6: Q10 = Q8@Q2 rows -> node slab bf16 (Q10 never stored) ----
  {
    float a0 = 0.f, a1 = 0.f, a2 = 0.f, a3 = 0.f;
    const float* Ar = Q8 + (size_t)i0 * 256;
#pragma unroll 8
    for (int k4 = 0; k4 < 64; ++k4) {
      const int k = k4 * 4;
      const float4 r0 = *(const float4*)(Ar + k);
      const float4 r1 = *(const float4*)(Ar + 256 + k);
      const float4 r2 = *(const float4*)(Ar + 512 + k);
      const float4 r3 = *(const float4*)(Ar + 768 + k);
      const float b0 = Q2[(k + 0) * 256 + j], b1 = Q2[(k + 1) * 256 + j];
      const float b2 = Q2[(k + 2) * 256 + j], b3 = Q2[(k + 3) * 256 + j];
      a0 = fmaf(r0.x, b0, fmaf(r0.y, b1, fmaf(r0.z, b2, fmaf(r0.w, b3, a0))));
      a1 = fmaf(r1.x, b0, fmaf(r1.y, b1, fmaf(r1.z, b2, fmaf(r1.w, b3, a1))));
      a2 = fmaf(r2.x, b0, fmaf(r2.y, b1, fmaf(r2.z, b2, fmaf(r2.w, b3, a2))));
      a3 = fmaf(r3.x, b0, fmaf(r3.y, b1, fmaf(r3.z, b2, fmaf(r3.w, b3, a3))));
    }
    // slab frag: B[kd][o] = P10[kd][o] = Q10[o][kd]; kd=j, o=i0+r
    const int kc = j >> 5, quad = (j >> 3) & 3, q8i = j & 7;
    const float av[4] = {a0, a1, a2, a3};
#pragma unroll
    for (int r = 0; r < 4; ++r) {
      const int o = i0 + r;
      slab[(12 + (o >> 7)) * 32768 + ((kc * 4 + quad) * 128 + (o & 127)) * 8 + q8i] = f2bf(av[r]);
    }
  }

  // ---- block 0: c-chain via transposed duals (coalesced column reads) ----
  if (blk == 0) {
    sv[j] = bode[j];
    __syncthreads();
    float acc = 0.f;
#pragma unroll 8
    for (int k4 = 0; k4 < 64; ++k4) {
      const int k = k4 * 4;
      const float4 bv = *(const float4*)&sv[k];
      acc = fmaf(bv.x, fmaf(0.05f, T_W[(k+0)*256+j], fmaf(1.6666667e-3f, T_Wp2[(k+0)*256+j], 4.1666667e-5f * T_Wp3[(k+0)*256+j])), acc);
      acc = fmaf(bv.y, fmaf(0.05f, T_W[(k+1)*256+j], fmaf(1.6666667e-3f, T_Wp2[(k+1)*256+j], 4.1666667e-5f * T_Wp3[(k+1)*256+j])), acc);
      acc = fmaf(bv.z, fmaf(0.05f, T_W[(k+2)*256+j], fmaf(1.6666667e-3f, T_Wp2[(k+2)*256+j], 4.1666667e-5f * T_Wp3[(k+2)*256+j])), acc);
      acc = fmaf(bv.w, fmaf(0.05f, T_W[(k+3)*256+j], fmaf(1.6666667e-3f, T_Wp2[(k+3)*256+j], 4.1666667e-5f * T_Wp3[(k+3)*256+j])), acc);
    }
    const float c1v = 0.1f * (bode[j] + acc);

    float c2v = c1v;
    __syncthreads(); sv[j] = c1v; __syncthreads();
#pragma unroll 8
    for (int k4 = 0; k4 < 64; ++k4) {
      const int k = k4 * 4;
      const float4 bv = *(const float4*)&sv[k];
      c2v = fmaf(bv.x, T_Mn[(k+0)*256+j], c2v);
      c2v = fmaf(bv.y, T_Mn[(k+1)*256+j], c2v);
      c2v = fmaf(bv.z, T_Mn[(k+2)*256+j], c2v);
      c2v = fmaf(bv.w, T_Mn[(k+3)*256+j], c2v);
    }
    float c4v = c2v;
    __syncthreads(); sv[j] = c2v; __syncthreads();
#pragma unroll 8
    for (int k4 = 0; k4 < 64; ++k4) {
      const int k = k4 * 4;
      const float4 bv = *(const float4*)&sv[k];
      c4v = fmaf(bv.x, T_Q2[(k+0)*256+j], c4v);
      c4v = fmaf(bv.y, T_Q2[(k+1)*256+j], c4v);
      c4v = fmaf(bv.z, T_Q2[(k+2)*256+j], c4v);
      c4v = fmaf(bv.w, T_Q2[(k+3)*256+j], c4v);
    }
    float c8v = c4v;
    __syncthreads(); sv[j] = c4v; __syncthreads();
#pragma unroll 8
    for (int k4 = 0; k4 < 64; ++k4) {
      const int k = k4 * 4;
      const float4 bv = *(const float4*)&sv[k];
      c8v = fmaf(bv.x, T_Q4[(k+0)*256+j], c8v);
      c8v = fmaf(bv.y, T_Q4[(k+1)*256+j], c8v);
      c8v = fmaf(bv.z, T_Q4[(k+2)*256+j], c8v);
      c8v = fmaf(bv.w, T_Q4[(k+3)*256+j], c8v);
    }
    float c10v = c2v;
    __syncthreads(); sv[j] = c8v; __syncthreads();
#pragma unroll 8
    for (int k4 = 0; k4 < 64; ++k4) {
      const int k = k4 * 4;
      const float4 bv = *(const float4*)&sv[k];
      c10v = fmaf(bv.x, T_Q2[(k+0)*256+j], c10v);
      c10v = fmaf(bv.y, T_Q2[(k+1)*256+j], c10v);
      c10v = fmaf(bv.z, T_Q2[(k+2)*256+j], c10v);
      c10v = fmaf(bv.w, T_Q2[(k+3)*256+j], c10v);
    }
    c10g[j] = c10v;
  }
}

// ---------------- fused main kernel ----------------
// grid 512 = 64 batches x 8 t-chunks of 64. 256 threads = 4 waves.
// A from LDS (X tile), B from L2 (slab, fragment order) with per-slice
// register prefetch of all 16 fragments (loads in flight across MFMA loop).
__global__ __launch_bounds__(256, 2) void k_main(
    const int* __restrict__ ids, const float* __restrict__ emb,
    const unsigned short* __restrict__ slab, const float* __restrict__ ctot,
    const float* __restrict__ b3, const float* __restrict__ g3, const float* __restrict__ be3,
    const float* __restrict__ b4, const float* __restrict__ g4, const float* __restrict__ be4,
    const float* __restrict__ b5, const float* __restrict__ g5, const float* __restrict__ be5,
    unsigned* __restrict__ featbuf) {
  __shared__ alignas(16) unsigned short Xt[68 * 264];
  __shared__ int ids_s[68];
  const int tid = threadIdx.x;
  const int blk = blockIdx.x;
  const int b = blk >> 3;
  const int t0 = (blk & 7) * 64;
  const int lane = tid & 63;
  const int wave = tid >> 6;
  const int m15 = lane & 15;
  const int quad = lane >> 4;

  if (tid < 68) {
    int t = t0 + tid;
    ids_s[tid] = (t < 512) ? ids[b * 512 + t] : -1;
  }
  __syncthreads();
  for (int i = tid; i < 68 * 64; i += 256) {
    int row = i >> 6, s4 = i & 63;
    uint2 v = make_uint2(0u, 0u);
    int id = ids_s[row];
    if (id >= 0) {
      const float4 f = *(const float4*)(emb + (size_t)id * 256 + s4 * 4);
      v.x = (unsigned)f2bf(f.x) | ((unsigned)f2bf(f.y) << 16);
      v.y = (unsigned)f2bf(f.z) | ((unsigned)f2bf(f.w) << 16);
    }
    *(uint2*)&Xt[row * 264 + s4 * 4] = v;
  }
  __syncthreads();

  const int g_start[5] = {0, 3, 7, 12, 13};
  const int g_cnt[5]   = {3, 4, 5, 1, 1};

  for (int g = 0; g < 5; ++g) {
    f32x4 acc[4][2];
#pragma unroll
    for (int mt = 0; mt < 4; ++mt)
#pragma unroll
      for (int nt = 0; nt < 2; ++nt)
        acc[mt][nt] = (f32x4){0.f, 0.f, 0.f, 0.f};

    for (int ji = 0; ji < g_cnt[g]; ++ji) {
      const int slice = g_start[g] + ji;
      const int shift = (g < 3) ? ji : 0;
      const unsigned short* bsl = slab + (size_t)slice * 32768 + quad * 1024 + wave * 256 + m15 * 8;
      // prefetch all 16 B fragments for this slice (16 dwordx4 in flight)
      bf16x8 bfr0[8], bfr1[8];
#pragma unroll
      for (int kc = 0; kc < 8; ++kc) {
        bfr0[kc] = *(const bf16x8*)&bsl[kc * 4096];
        bfr1[kc] = *(const bf16x8*)&bsl[kc * 4096 + 128];
      }
#pragma unroll
      for (int kc = 0; kc < 8; ++kc) {
        const int kd0 = kc * 32 + quad * 8;
        bf16x8 af[4];
#pragma unroll
        for (int mt = 0; mt < 4; ++mt)
          af[mt] = *(const bf16x8*)&Xt[(shift + mt * 16 + m15) * 264 + kd0];
#pragma unroll
        for (int mt = 0; mt < 4; ++mt)
          acc[mt][0] = __builtin_amdgcn_mfma_f32_16x16x32_bf16(af[mt], bfr0[kc], acc[mt][0], 0, 0, 0);
#pragma unroll
        for (int mt = 0; mt < 4; ++mt)
          acc[mt][1] = __builtin_amdgcn_mfma_f32_16x16x32_bf16(af[mt], bfr1[kc], acc[mt][1], 0, 0, 0);
      }
    }

    // epilogue: C/D layout col=lane&15, row=(lane>>4)*4+reg
    if (g < 3) {
      const int k = g + 3;
      const float* bb  = (g == 0) ? b3 : (g == 1) ? b4 : b5;
      const float* gg  = (g == 0) ? g3 : (g == 1) ? g4 : g5;
      const float* bbe = (g == 0) ? be3 : (g == 1) ? be4 : be5;
      const int off = 256 + g * 128;
      const int tmax = 512 - k;
#pragma unroll
      for (int nt = 0; nt < 2; ++nt) {
        const int n = (wave * 2 + nt) * 16 + m15;
        const float sc = gg[n] * 0.9999950000375f;  // g * 1/sqrt(1+1e-5)
        const float sh = fmaf(sc, bb[n], bbe[n]);
        float mx = 0.f;  // relu floor doubles as init
#pragma unroll
        for (int mt = 0; mt < 4; ++mt)
#pragma unroll
          for (int r = 0; r < 4; ++r) {
            const int t = t0 + mt * 16 + quad * 4 + r;
            const float v = fmaf(sc, acc[mt][nt][r], sh);
            if (t <= tmax) mx = fmaxf(mx, v);
          }
        mx = fmaxf(mx, __shfl_xor(mx, 16));
        mx = fmaxf(mx, __shfl_xor(mx, 32));
        if (quad == 0) atomicMax(&featbuf[b * 640 + off + n], __float_as_uint(mx));
      }
    } else {
      const int base = (g == 3) ? 0 : 128;
#pragma unroll
      for (int nt = 0; nt < 2; ++nt) {
        const int n = (wave * 2 + nt) * 16 + m15;
        const float ct = ctot[base + n];
        float mx = -3.4e38f;
#pragma unroll
        for (int mt = 0; mt < 4; ++mt)
#pragma unroll
          for (int r = 0; r < 4; ++r)
            mx = fmaxf(mx, acc[mt][nt][r] + ct);
        mx = fmaxf(mx, __shfl_xor(mx, 16));
        mx = fmaxf(mx, __shfl_xor(mx, 32));
        if (quad == 0) {
          unsigned bits = __float_as_uint(mx);
          unsigned key = (bits & 0x80000000u) ? ~bits : (bits | 0x80000000u);
          atomicMax(&featbuf[b * 640 + base + n], key);
        }
      }
    }
  }
}

// ---------------- classifier ----------------
__global__ void k_fin(const unsigned* __restrict__ featbuf, const float* __restrict__ wc,
                      const float* __restrict__ bc, float* __restrict__ out) {
  int b = blockIdx.x, lane = threadIdx.x;  // 64 threads = 1 wave
  float p[10];
#pragma unroll
  for (int c = 0; c < 10; ++c) p[c] = 0.f;
  for (int f = lane; f < 640; f += 64) {
    unsigned u = featbuf[b * 640 + f];
    float v;
    if (f < 256) v = (u & 0x80000000u) ? __uint_as_float(u ^ 0x80000000u) : __uint_as_float(~u);
    else v = __uint_as_float(u);
#pragma unroll
    for (int c = 0; c < 10; ++c) p[c] = fmaf(v, wc[c * 640 + f], p[c]);
  }
#pragma unroll
  for (int c = 0; c < 10; ++c) {
    float s = p[c];
#pragma unroll
    for (int off = 32; off > 0; off >>= 1) s += __shfl_down(s, off);
    if (lane == 0) out[b * 10 + c] = s + bc[c];
  }
}

// ---------------- launcher ----------------
extern "C" void kernel_launch(void* const* d_in, const int* in_sizes, int n_in,
                              void* d_out, int out_size, void* d_ws, size_t ws_size,
                              hipStream_t stream) {
  (void)in_sizes; (void)n_in; (void)out_size; (void)ws_size;
  const int*   ids  = (const int*)d_in[0];
  const float* emb  = (const float*)d_in[1];
  const float* W    = (const float*)d_in[2];
  const float* bode = (const float*)d_in[3];
  const float* w3   = (const float*)d_in[4];
  const float* b3   = (const float*)d_in[5];
  const float* g3   = (const float*)d_in[6];
  const float* be3  = (const float*)d_in[7];
  const float* w4   = (const float*)d_in[8];
  const float* b4   = (const float*)d_in[9];
  const float* g4   = (const float*)d_in[10];
  const float* be4  = (const float*)d_in[11];
  const float* w5   = (const float*)d_in[12];
  const float* b5   = (const float*)d_in[13];
  const float* g5   = (const float*)d_in[14];
  const float* be5  = (const float*)d_in[15];
  const float* wc   = (const float*)d_in[16];
  const float* bc   = (const float*)d_in[17];
  float* out = (float*)d_out;

  float* wsf = (float*)d_ws;
  unsigned* cnt  = (unsigned*)wsf;                      // slot 0
  unsigned* flag = (unsigned*)wsf + 32;                 // separate cache line
  unsigned* featbuf = (unsigned*)(wsf + 64);            // 64*640 uints
  float* mat = wsf + 65536;                             // 852224 floats
  unsigned short* slab = (unsigned short*)(mat + 852224); // 14 slices * 32768 bf16
  const float* c10 = mat + 851968;

  (void)hipMemsetAsync(cnt, 0, (64 + 64 * 640) * sizeof(unsigned), stream);

  hipLaunchKernelGGL(k_prep, dim3(NBLK), dim3(256), 0, stream,
                     W, bode, w3, w4, w5, mat, slab, cnt, flag);
  hipLaunchKernelGGL(k_main, dim3(512), dim3(256), 0, stream,
                     ids, emb, slab, c10,
                     b3, g3, be3, b4, g4, be4, b5, g5, be5, featbuf);
  hipLaunchKernelGGL(k_fin, dim3(64), dim3(64), 0, stream, featbuf, wc, bc, out);
}

// Round 6
// 296.746 us; speedup vs baseline: 1.1340x; 1.1340x over previous
//
#include <hip/hip_runtime.h>

// B=64, S=512, D=256, VOCAB=50000, NC=10, N_STEPS=10 (h=0.1), BN eval.
// RK4 on linear RHS == affine map; 10 steps collapse to z@P10 + c10.
// Round 6: (a) k_main reverted to round-1 LDS-staged-B design (measured 62us;
// global-B variants measured ~160us -- likely compiler spill of prefetch regs);
// (b) prep: 128 blocks x 2 rows, B staged through LDS in 32-row chunks
// (coalesced float4 global reads + conflict-free LDS column reads), 5 phases /
// 4 grid barriers, Q8/Wp3/Wp4 never materialized.

typedef short bf16x8 __attribute__((ext_vector_type(8)));
typedef float f32x4 __attribute__((ext_vector_type(4)));

#define NBLK 128

__device__ __forceinline__ unsigned short f2bf(float f) {
  unsigned u = __float_as_uint(f);
  u += 0x7FFFu + ((u >> 16) & 1u);   // RNE; inputs are normal floats
  return (unsigned short)(u >> 16);
}

// grid barrier: RELAXED polling (no per-poll invalidate), one acquire on exit.
__device__ __forceinline__ void gsync(unsigned* cnt, unsigned* flag, unsigned phase) {
  __syncthreads();
  if (threadIdx.x == 0) {
    unsigned old = __hip_atomic_fetch_add(cnt, 1u, __ATOMIC_RELEASE, __HIP_MEMORY_SCOPE_AGENT);
    if (old == phase * NBLK - 1)
      __hip_atomic_store(flag, phase, __ATOMIC_RELEASE, __HIP_MEMORY_SCOPE_AGENT);
    while (__hip_atomic_load(flag, __ATOMIC_RELAXED, __HIP_MEMORY_SCOPE_AGENT) < phase)
      __builtin_amdgcn_s_sleep(2);
    (void)__hip_atomic_load(flag, __ATOMIC_ACQUIRE, __HIP_MEMORY_SCOPE_AGENT);
  }
  __syncthreads();
}

// ---------------- prep helpers ----------------
// Load 2 A-rows into LDS (coalesced float4), with trailing barrier.
__device__ __forceinline__ void load_arows(const float* __restrict__ A, int i0,
                                           float* sA0, float* sA1, int j) {
  if (j < 64)       ((float4*)sA0)[j]      = ((const float4*)(A + (size_t)i0 * 256))[j];
  else if (j < 128) ((float4*)sA1)[j - 64] = ((const float4*)(A + (size_t)(i0 + 1) * 256))[j - 64];
  __syncthreads();
}

// acc rows (a0,a1) += (sA0,sA1) @ B ; B staged through sB in 8 chunks of 32 rows.
// sB column reads: bank = j%32, 2 lanes/bank (free). Staging: coalesced float4.
__device__ __forceinline__ void mm2(const float* __restrict__ Bm, float* sB,
                                    const float* sA0, const float* sA1,
                                    float& a0, float& a1, int j) {
  for (int c = 0; c < 8; ++c) {
    __syncthreads();
#pragma unroll
    for (int i = 0; i < 8; ++i)
      ((float4*)sB)[i * 256 + j] = ((const float4*)(Bm + (size_t)c * 8192))[i * 256 + j];
    __syncthreads();
#pragma unroll 8
    for (int k = 0; k < 32; ++k) {
      const float b = sB[k * 256 + j];
      a0 = fmaf(sA0[c * 32 + k], b, a0);
      a1 = fmaf(sA1[c * 32 + k], b, a1);
    }
  }
}

// ---------------- fused prep: 128 blocks x 2 rows, 4 grid barriers ----------------
// mat layout (65536 floats each): Wp2,T_W,T_Wp2,T_Wp3,Mn,T_Mn,Q2,T_Q2,Q4,T_Q4; c10g after.
// N-space: Mn = Taylor4(0.1*W) (untransposed); step matrix = Mn^T, so
// z_new[j] = sum_k z[k]*Mn[j][k]; c-chain contracts with Mn[j][k] = T[k*256+j].
__global__ __launch_bounds__(256, 1) void k_prep(
    const float* __restrict__ W, const float* __restrict__ bode,
    const float* __restrict__ w3, const float* __restrict__ w4, const float* __restrict__ w5,
    float* mat, unsigned short* slab, unsigned* cnt, unsigned* flag) {
  float* Wp2   = mat;
  float* T_W   = mat + 65536;
  float* T_Wp2 = mat + 131072;
  float* T_Wp3 = mat + 196608;
  float* Mn    = mat + 262144;
  float* T_Mn  = mat + 327680;
  float* Q2    = mat + 393216;
  float* T_Q2  = mat + 458752;
  float* Q4    = mat + 524288;
  float* T_Q4  = mat + 589824;
  float* c10g  = mat + 655360;

  const int blk = blockIdx.x;
  const int j = threadIdx.x;
  const int i0 = blk * 2;

  __shared__ float sB[32 * 256];   // 32 KB chunk buffer
  __shared__ float sA0[256];
  __shared__ float sA1[256];
  __shared__ float sv[256];

  // ---- S1: Wp2 = W@W ; duals T_W, T_Wp2 ; conv repack ----
  load_arows(W, i0, sA0, sA1, j);
  {
    float a0 = 0.f, a1 = 0.f;
    mm2(W, sB, sA0, sA1, a0, a1, j);
    Wp2[(size_t)i0 * 256 + j] = a0;
    Wp2[(size_t)(i0 + 1) * 256 + j] = a1;
    *(float2*)(T_Wp2 + (size_t)j * 256 + i0) = make_float2(a0, a1);
    *(float2*)(T_W + (size_t)j * 256 + i0) = make_float2(sA0[j], sA1[j]);
  }
  for (int e = blk * 256 + j; e < 12 * 32768; e += NBLK * 256) {
    int s = e >> 15, r = e & 32767, kd = r >> 7, o = r & 127;
    const float* w; int kk, jj;
    if (s < 3)      { w = w3; kk = 3; jj = s; }
    else if (s < 7) { w = w4; kk = 4; jj = s - 3; }
    else            { w = w5; kk = 5; jj = s - 7; }
    float val = w[(o * 256 + kd) * kk + jj];
    int kc = kd >> 5, quad = (kd >> 3) & 3, q8 = kd & 7;
    slab[s * 32768 + ((kc * 4 + quad) * 128 + o) * 8 + q8] = f2bf(val);
  }
  gsync(cnt, flag, 1);

  // ---- S2: Wp3 = Wp2@W, Wp4 = Wp2@Wp2 (rows, registers only); Mn rows ----
  load_arows(Wp2, i0, sA0, sA1, j);
  {
    float p30 = 0.f, p31 = 0.f, p40 = 0.f, p41 = 0.f;
    mm2(W, sB, sA0, sA1, p30, p31, j);
    mm2(Wp2, sB, sA0, sA1, p40, p41, j);
    *(float2*)(T_Wp3 + (size_t)j * 256 + i0) = make_float2(p30, p31);
    const float w0 = W[(size_t)i0 * 256 + j], w1 = W[(size_t)(i0 + 1) * 256 + j];
    // Mn = I + 0.1W + 0.005 W^2 + W^3/6000 + W^4/240000
    const float m0 = (i0 == j ? 1.f : 0.f) + 0.1f * w0 + 0.005f * sA0[j]
                     + p30 * (1.f / 6000.f) + p40 * (1.f / 240000.f);
    const float m1 = ((i0 + 1) == j ? 1.f : 0.f) + 0.1f * w1 + 0.005f * sA1[j]
                     + p31 * (1.f / 6000.f) + p41 * (1.f / 240000.f);
    Mn[(size_t)i0 * 256 + j] = m0;
    Mn[(size_t)(i0 + 1) * 256 + j] = m1;
    *(float2*)(T_Mn + (size_t)j * 256 + i0) = make_float2(m0, m1);
  }
  gsync(cnt, flag, 2);

  // ---- S3: Q2 = Mn@Mn ----
  load_arows(Mn, i0, sA0, sA1, j);
  {
    float a0 = 0.f, a1 = 0.f;
    mm2(Mn, sB, sA0, sA1, a0, a1, j);
    Q2[(size_t)i0 * 256 + j] = a0;
    Q2[(size_t)(i0 + 1) * 256 + j] = a1;
    *(float2*)(T_Q2 + (size_t)j * 256 + i0) = make_float2(a0, a1);
  }
  gsync(cnt, flag, 3);

  // ---- S4: Q4 = Q2@Q2 ----
  load_arows(Q2, i0, sA0, sA1, j);
  {
    float a0 = 0.f, a1 = 0.f;
    mm2(Q2, sB, sA0, sA1, a0, a1, j);
    Q4[(size_t)i0 * 256 + j] = a0;
    Q4[(size_t)(i0 + 1) * 256 + j] = a1;
    *(float2*)(T_Q4 + (size_t)j * 256 + i0) = make_float2(a0, a1);
  }
  gsync(cnt, flag, 4);

  // ---- S5: q8 rows = Q4row@Q4 ; q10 rows = q8row@Q2 -> node slab. No barrier. ----
  load_arows(Q4, i0, sA0, sA1, j);
  {
    float q80 = 0.f, q81 = 0.f;
    mm2(Q4, sB, sA0, sA1, q80, q81, j);
    __syncthreads();                 // all reads of sA0/sA1 done before overwrite
    sA0[j] = q80; sA1[j] = q81;
    __syncthreads();
    float a0 = 0.f, a1 = 0.f;
    mm2(Q2, sB, sA0, sA1, a0, a1, j);
    // slab node frag: B[kd][o] = Q10[o][kd]; rows o = i0,i0+1; kd = j
    const int kc = j >> 5, quad = (j >> 3) & 3, q8i = j & 7;
    slab[(12 + (i0 >> 7)) * 32768 + ((kc * 4 + quad) * 128 + (i0 & 127)) * 8 + q8i] = f2bf(a0);
    slab[(12 + ((i0 + 1) >> 7)) * 32768 + ((kc * 4 + quad) * 128 + ((i0 + 1) & 127)) * 8 + q8i] = f2bf(a1);
  }

  // ---- block 0: c-chain via transposed duals (coalesced across lanes) ----
  if (blk == 0) {
    __syncthreads();
    sv[j] = bode[j];
    __syncthreads();
    float acc = 0.f;
#pragma unroll 8
    for (int k4 = 0; k4 < 64; ++k4) {
      const int k = k4 * 4;
      const float4 bv = *(const float4*)&sv[k];
      acc = fmaf(bv.x, fmaf(0.05f, T_W[(k+0)*256+j], fmaf(1.6666667e-3f, T_Wp2[(k+0)*256+j], 4.1666667e-5f * T_Wp3[(k+0)*256+j])), acc);
      acc = fmaf(bv.y, fmaf(0.05f, T_W[(k+1)*256+j], fmaf(1.6666667e-3f, T_Wp2[(k+1)*256+j], 4.1666667e-5f * T_Wp3[(k+1)*256+j])), acc);
      acc = fmaf(bv.z, fmaf(0.05f, T_W[(k+2)*256+j], fmaf(1.6666667e-3f, T_Wp2[(k+2)*256+j], 4.1666667e-5f * T_Wp3[(k+2)*256+j])), acc);
      acc = fmaf(bv.w, fmaf(0.05f, T_W[(k+3)*256+j], fmaf(1.6666667e-3f, T_Wp2[(k+3)*256+j], 4.1666667e-5f * T_Wp3[(k+3)*256+j])), acc);
    }
    const float c1v = 0.1f * (bode[j] + acc);

    float c2v = c1v;
    __syncthreads(); sv[j] = c1v; __syncthreads();
#pragma unroll 8
    for (int k4 = 0; k4 < 64; ++k4) {
      const int k = k4 * 4;
      const float4 bv = *(const float4*)&sv[k];
      c2v = fmaf(bv.x, T_Mn[(k+0)*256+j], c2v);
      c2v = fmaf(bv.y, T_Mn[(k+1)*256+j], c2v);
      c2v = fmaf(bv.z, T_Mn[(k+2)*256+j], c2v);
      c2v = fmaf(bv.w, T_Mn[(k+3)*256+j], c2v);
    }
    float c4v = c2v;
    __syncthreads(); sv[j] = c2v; __syncthreads();
#pragma unroll 8
    for (int k4 = 0; k4 < 64; ++k4) {
      const int k = k4 * 4;
      const float4 bv = *(const float4*)&sv[k];
      c4v = fmaf(bv.x, T_Q2[(k+0)*256+j], c4v);
      c4v = fmaf(bv.y, T_Q2[(k+1)*256+j], c4v);
      c4v = fmaf(bv.z, T_Q2[(k+2)*256+j], c4v);
      c4v = fmaf(bv.w, T_Q2[(k+3)*256+j], c4v);
    }
    float c8v = c4v;
    __syncthreads(); sv[j] = c4v; __syncthreads();
#pragma unroll 8
    for (int k4 = 0; k4 < 64; ++k4) {
      const int k = k4 * 4;
      const float4 bv = *(const float4*)&sv[k];
      c8v = fmaf(bv.x, T_Q4[(k+0)*256+j], c8v);
      c8v = fmaf(bv.y, T_Q4[(k+1)*256+j], c8v);
      c8v = fmaf(bv.z, T_Q4[(k+2)*256+j], c8v);
      c8v = fmaf(bv.w, T_Q4[(k+3)*256+j], c8v);
    }
    float c10v = c2v;
    __syncthreads(); sv[j] = c8v; __syncthreads();
#pragma unroll 8
    for (int k4 = 0; k4 < 64; ++k4) {
      const int k = k4 * 4;
      const float4 bv = *(const float4*)&sv[k];
      c10v = fmaf(bv.x, T_Q2[(k+0)*256+j], c10v);
      c10v = fmaf(bv.y, T_Q2[(k+1)*256+j], c10v);
      c10v = fmaf(bv.z, T_Q2[(k+2)*256+j], c10v);
      c10v = fmaf(bv.w, T_Q2[(k+3)*256+j], c10v);
    }
    c10g[j] = c10v;
  }
}

// ---------------- fused main kernel (round-1 design, measured 62us) ----------------
// grid 512 = 64 batches x 8 t-chunks of 64. 256 threads = 4 waves.
// LDS: X tile 68x264 bf16 (+8 pad), B tile 16 KB staged per (slice, kcq).
__global__ __launch_bounds__(256, 2) void k_main(
    const int* __restrict__ ids, const float* __restrict__ emb,
    const unsigned short* __restrict__ slab, const float* __restrict__ ctot,
    const float* __restrict__ b3, const float* __restrict__ g3, const float* __restrict__ be3,
    const float* __restrict__ b4, const float* __restrict__ g4, const float* __restrict__ be4,
    const float* __restrict__ b5, const float* __restrict__ g5, const float* __restrict__ be5,
    unsigned* __restrict__ featbuf) {
  __shared__ alignas(16) unsigned short Xt[68 * 264];
  __shared__ alignas(16) unsigned short Bt[8192];
  __shared__ int ids_s[68];
  const int tid = threadIdx.x;
  const int blk = blockIdx.x;
  const int b = blk >> 3;
  const int t0 = (blk & 7) * 64;
  const int lane = tid & 63;
  const int wave = tid >> 6;
  const int m15 = lane & 15;
  const int quad = lane >> 4;

  if (tid < 68) {
    int t = t0 + tid;
    ids_s[tid] = (t < 512) ? ids[b * 512 + t] : -1;
  }
  __syncthreads();
  for (int i = tid; i < 68 * 64; i += 256) {
    int row = i >> 6, s4 = i & 63;
    uint2 v = make_uint2(0u, 0u);
    int id = ids_s[row];
    if (id >= 0) {
      const float4 f = *(const float4*)(emb + (size_t)id * 256 + s4 * 4);
      v.x = (unsigned)f2bf(f.x) | ((unsigned)f2bf(f.y) << 16);
      v.y = (unsigned)f2bf(f.z) | ((unsigned)f2bf(f.w) << 16);
    }
    *(uint2*)&Xt[row * 264 + s4 * 4] = v;
  }

  const int g_start[5] = {0, 3, 7, 12, 13};
  const int g_cnt[5]   = {3, 4, 5, 1, 1};

  for (int g = 0; g < 5; ++g) {
    f32x4 acc[4][2];
#pragma unroll
    for (int mt = 0; mt < 4; ++mt)
#pragma unroll
      for (int nt = 0; nt < 2; ++nt)
        acc[mt][nt] = (f32x4){0.f, 0.f, 0.f, 0.f};

    for (int ji = 0; ji < g_cnt[g]; ++ji) {
      const int slice = g_start[g] + ji;
      const int shift = (g < 3) ? ji : 0;
      for (int kcq = 0; kcq < 4; ++kcq) {
        __syncthreads();  // protect Bt readers of previous stage (and X staging, first time)
        {
          const uint4* src = (const uint4*)(slab + (size_t)slice * 32768 + kcq * 8192);
          uint4* dst = (uint4*)Bt;
#pragma unroll
          for (int r = 0; r < 4; ++r) dst[r * 256 + tid] = src[r * 256 + tid];
        }
        __syncthreads();
#pragma unroll
        for (int kc2 = 0; kc2 < 2; ++kc2) {
          const int kd0 = (kcq * 2 + kc2) * 32 + quad * 8;
          bf16x8 af[4];
#pragma unroll
          for (int mt = 0; mt < 4; ++mt)
            af[mt] = *(const bf16x8*)&Xt[(shift + mt * 16 + m15) * 264 + kd0];
#pragma unroll
          for (int nt = 0; nt < 2; ++nt) {
            const bf16x8 bfr =
                *(const bf16x8*)&Bt[((kc2 * 4 + quad) * 128 + (wave * 2 + nt) * 16 + m15) * 8];
#pragma unroll
            for (int mt = 0; mt < 4; ++mt)
              acc[mt][nt] = __builtin_amdgcn_mfma_f32_16x16x32_bf16(af[mt], bfr, acc[mt][nt], 0, 0, 0);
          }
        }
      }
    }

    // epilogue: C/D layout col=lane&15, row=(lane>>4)*4+reg
    if (g < 3) {
      const int k = g + 3;
      const float* bb  = (g == 0) ? b3 : (g == 1) ? b4 : b5;
      const float* gg  = (g == 0) ? g3 : (g == 1) ? g4 : g5;
      const float* bbe = (g == 0) ? be3 : (g == 1) ? be4 : be5;
      const int off = 256 + g * 128;   // feats: [node 256][p3 128][p4 128][p5 128]
      const int tmax = 512 - k;
#pragma unroll
      for (int nt = 0; nt < 2; ++nt) {
        const int n = (wave * 2 + nt) * 16 + m15;
        const float sc = gg[n] * 0.9999950000375f;  // g * 1/sqrt(1+1e-5)
        const float sh = fmaf(sc, bb[n], bbe[n]);
        float mx = 0.f;  // relu floor doubles as init
#pragma unroll
        for (int mt = 0; mt < 4; ++mt)
#pragma unroll
          for (int r = 0; r < 4; ++r) {
            const int t = t0 + mt * 16 + quad * 4 + r;
            const float v = fmaf(sc, acc[mt][nt][r], sh);
            if (t <= tmax) mx = fmaxf(mx, v);
          }
        mx = fmaxf(mx, __shfl_xor(mx, 16));
        mx = fmaxf(mx, __shfl_xor(mx, 32));
        if (quad == 0) atomicMax(&featbuf[b * 640 + off + n], __float_as_uint(mx));
      }
    } else {
      const int base = (g == 3) ? 0 : 128;
#pragma unroll
      for (int nt = 0; nt < 2; ++nt) {
        const int n = (wave * 2 + nt) * 16 + m15;
        const float ct = ctot[base + n];
        float mx = -3.4e38f;
#pragma unroll
        for (int mt = 0; mt < 4; ++mt)
#pragma unroll
          for (int r = 0; r < 4; ++r)
            mx = fmaxf(mx, acc[mt][nt][r] + ct);
        mx = fmaxf(mx, __shfl_xor(mx, 16));
        mx = fmaxf(mx, __shfl_xor(mx, 32));
        if (quad == 0) {
          unsigned bits = __float_as_uint(mx);
          unsigned key = (bits & 0x80000000u) ? ~bits : (bits | 0x80000000u);  // order-preserving
          atomicMax(&featbuf[b * 640 + base + n], key);
        }
      }
    }
  }
}

// ---------------- classifier ----------------
__global__ void k_fin(const unsigned* __restrict__ featbuf, const float* __restrict__ wc,
                      const float* __restrict__ bc, float* __restrict__ out) {
  int b = blockIdx.x, lane = threadIdx.x;  // 64 threads = 1 wave
  float p[10];
#pragma unroll
  for (int c = 0; c < 10; ++c) p[c] = 0.f;
  for (int f = lane; f < 640; f += 64) {
    unsigned u = featbuf[b * 640 + f];
    float v;
    if (f < 256) v = (u & 0x80000000u) ? __uint_as_float(u ^ 0x80000000u) : __uint_as_float(~u);
    else v = __uint_as_float(u);
#pragma unroll
    for (int c = 0; c < 10; ++c) p[c] = fmaf(v, wc[c * 640 + f], p[c]);
  }
#pragma unroll
  for (int c = 0; c < 10; ++c) {
    float s = p[c];
#pragma unroll
    for (int off = 32; off > 0; off >>= 1) s += __shfl_down(s, off);
    if (lane == 0) out[b * 10 + c] = s + bc[c];
  }
}

// ---------------- launcher ----------------
extern "C" void kernel_launch(void* const* d_in, const int* in_sizes, int n_in,
                              void* d_out, int out_size, void* d_ws, size_t ws_size,
                              hipStream_t stream) {
  (void)in_sizes; (void)n_in; (void)out_size; (void)ws_size;
  const int*   ids  = (const int*)d_in[0];
  const float* emb  = (const float*)d_in[1];
  const float* W    = (const float*)d_in[2];
  const float* bode = (const float*)d_in[3];
  const float* w3   = (const float*)d_in[4];
  const float* b3   = (const float*)d_in[5];
  const float* g3   = (const float*)d_in[6];
  const float* be3  = (const float*)d_in[7];
  const float* w4   = (const float*)d_in[8];
  const float* b4   = (const float*)d_in[9];
  const float* g4   = (const float*)d_in[10];
  const float* be4  = (const float*)d_in[11];
  const float* w5   = (const float*)d_in[12];
  const float* b5   = (const float*)d_in[13];
  const float* g5   = (const float*)d_in[14];
  const float* be5  = (const float*)d_in[15];
  const float* wc   = (const float*)d_in[16];
  const float* bc   = (const float*)d_in[17];
  float* out = (float*)d_out;

  float* wsf = (float*)d_ws;
  unsigned* cnt  = (unsigned*)wsf;                        // slot 0
  unsigned* flag = (unsigned*)wsf + 32;                   // separate cache line
  unsigned* featbuf = (unsigned*)(wsf + 64);              // 64*640 uints
  float* mat = wsf + 65536;                               // 10*65536 + 256 floats
  unsigned short* slab = (unsigned short*)(mat + 655616); // 14 slices * 32768 bf16
  const float* c10 = mat + 655360;

  (void)hipMemsetAsync(cnt, 0, (64 + 64 * 640) * sizeof(unsigned), stream);

  hipLaunchKernelGGL(k_prep, dim3(NBLK), dim3(256), 0, stream,
                     W, bode, w3, w4, w5, mat, slab, cnt, flag);
  hipLaunchKernelGGL(k_main, dim3(512), dim3(256), 0, stream,
                     ids, emb, slab, c10,
                     b3, g3, be3, b4, g4, be4, b5, g5, be5, featbuf);
  hipLaunchKernelGGL(k_fin, dim3(64), dim3(64), 0, stream, featbuf, wc, bc, out);
}